// Round 2
// baseline (616.055 us; speedup 1.0000x reference)
//
#include <hip/hip_runtime.h>
#include <math.h>

#define BS   32
#define NV   6
#define MF   12
#define MT   16
#define NF   1992
#define NR   11
#define HID  128
#define RED  256
#define OUTD 90
#define GAMMA 0.1f
#define NZCAP 512   // E[nnz]=31.6, sigma=5.6 -> 512 is >80 sigma, bulletproof

typedef float f4_t __attribute__((ext_vector_type(4)));

// ---------------- workspace layout (float offsets) ----------------
#define WS_HG    0                        // 32*256
#define WS_HP    (WS_HG + BS*RED)         // 32*256  (hg+hp contiguous for zeroing)
#define WS_ATTN  (WS_HP + BS*RED)         // 2304
#define WS_FSUM  (WS_ATTN + BS*NV*MF)     // 2304
#define WS_REMB  (WS_FSUM + BS*NV*MF)     // 1992*256
#define WS_REDGE (WS_REMB + NF*RED)       // 11*256
#define WS_FCWT  (WS_REDGE + NR*RED)      // 512*90 (fc_W^T, j-major)
#define WS_DIAG  (WS_FCWT + 2*RED*OUTD)   // 256
#define WS_DONE  (WS_DIAG + RED)          // 32 ints (per-batch done tickets)

#define N_ZERO (2*BS*RED)                 // 16384
#define ZERO_ELEMS (N_ZERO + BS)          // + 32 done tickets
#define N_FCWT (2*RED*OUTD)               // 46080
#define ZERO_BLOCKS ((ZERO_ELEMS + 255)/256)   // 65
#define PREP2_BLOCKS ((N_FCWT + RED)/256)      // 181 (fcWT then diag, exact)
#define ATTN_BLOCKS (BS*NV)               // 192
#define NPB 8
#define REMB_BLOCKS (NF/NPB)              // 249
#define REDGE_BLOCKS 2                    // 11 rows -> 8+3
#define K1_BLOCKS (ZERO_BLOCKS+PREP2_BLOCKS+ATTN_BLOCKS+REMB_BLOCKS+REDGE_BLOCKS)

// ---------- K1: zero | fcWT+diag | attention | remb+redge (no LDS transpose) ----------
__global__ __launch_bounds__(256) void k1_prep_attn_reduce(
        const float* __restrict__ feat, const float* __restrict__ W_alpha,
        const float* __restrict__ b_alpha, const float* __restrict__ W_beta,
        const float* __restrict__ b_beta,
        const float* __restrict__ emb, const float* __restrict__ W_edge,
        const float* __restrict__ W_v, const float* __restrict__ W_r,
        const float* __restrict__ b_v, const float* __restrict__ b_r,
        const float* __restrict__ fc_W, const float* __restrict__ W_l,
        float* __restrict__ ws_base, int* __restrict__ done_b,
        float* __restrict__ fcWT, float* __restrict__ diag,
        float* __restrict__ attn_ws, float* __restrict__ fsum_ws,
        float* __restrict__ remb, float* __restrict__ redge) {
    int blk = blockIdx.x;
    int tid = threadIdx.x;

    // union of per-role shared: ~4.2 KB -> 8 blocks/CU for every role
    __shared__ float dot12[MF], fs12[MF];
    __shared__ float4 rows4[NPB][HID / 4];    // 4 KB: emb/W_edge rows, b128-broadcast

    if (blk < ZERO_BLOCKS) {                  // zero hg+hp + done tickets
        int i = blk * 256 + tid;
        if (i < N_ZERO) ws_base[i] = 0.f;
        else if (i < ZERO_ELEMS) done_b[i - N_ZERO] = 0;
        return;
    }
    blk -= ZERO_BLOCKS;

    if (blk < PREP2_BLOCKS) {                 // fcWT transpose + diag(W_l)
        int i = blk * 256 + tid;
        if (i < N_FCWT) {
            int jj = i / OUTD, o = i - jj * OUTD;
            fcWT[i] = fc_W[o * (2 * RED) + jj];
        } else {
            int j = i - N_FCWT;
            diag[j] = W_l[(size_t)j * RED + j];
        }
        return;
    }
    blk -= PREP2_BLOCKS;

    if (blk < ATTN_BLOCKS) {                  // one block per (b,v), wave per m
        int bv   = blk;
        int v    = bv % NV;
        int wave = tid >> 6;
        int lane = tid & 63;
        const float* base = feat + (size_t)bv * MF * NF;
        for (int m = wave; m < MF; m += 4) {
            const float4* rw = (const float4*)(base + (size_t)m * NF);
            const float4* wa = (const float4*)W_alpha;
            float da = 0.f, fs = 0.f;
            for (int i = lane; i < NF / 4; i += 64) {
                float4 x = rw[i];
                float4 w = wa[i];
                da += w.x * x.x + w.y * x.y + w.z * x.z + w.w * x.w;
                fs += x.x + x.y + x.z + x.w;
            }
            #pragma unroll
            for (int off = 32; off > 0; off >>= 1) {
                da += __shfl_xor(da, off);
                fs += __shfl_xor(fs, off);
            }
            if (lane == 0) { dot12[m] = da; fs12[m] = fs; }
        }
        __syncthreads();
        if (tid == 0) {
            float logits[MF];
            float mx = -1e30f;
            for (int m = 0; m < MF; ++m) { logits[m] = dot12[m] + b_alpha[m]; mx = fmaxf(mx, logits[m]); }
            float s = 0.f;
            for (int m = 0; m < MF; ++m) { logits[m] = expf(logits[m] - mx); s += logits[m]; }
            float inv = 1.f / s;
            float bdot = 0.f;
            for (int m = 0; m < MF; ++m) { logits[m] *= inv; bdot += W_beta[m] * logits[m]; }
            float lamb = expf(-GAMMA * (float)(NV - v));
            float beta = tanhf(bdot + b_beta[v]) * lamb;
            for (int m = 0; m < MF; ++m) {
                attn_ws[bv * MF + m] = logits[m] * beta;
                fsum_ws[bv * MF + m] = fs12[m];
            }
        }
        return;
    }
    blk -= ATTN_BLOCKS;

    // ---- remb (emb @ W_v^T + b_v) and redge (W_edge @ W_r^T + b_r) ----
    // thread r reads W_v row r directly (float4, L1 line reuse x4);
    // emb rows staged once in LDS, read as broadcast ds_read_b128.
    bool isEdge = (blk >= REMB_BLOCKS);
    const float* src  = isEdge ? W_edge : emb;
    const float* Wm   = isEdge ? W_r : W_v;
    const float* bias = isEdge ? b_r : b_v;
    float* dst        = isEdge ? redge : remb;
    int n0    = (isEdge ? (blk - REMB_BLOCKS) : blk) * NPB;
    int rowsN = isEdge ? min(NPB, NR - n0) : NPB;

    const float4* src4 = (const float4*)(src + (size_t)n0 * HID);
    for (int idx = tid; idx < NPB * (HID / 4); idx += 256) {
        int j = idx >> 5, k4 = idx & 31;
        float4 z4 = {0.f, 0.f, 0.f, 0.f};
        rows4[j][k4] = (j < rowsN) ? src4[idx] : z4;
    }
    __syncthreads();

    int r = tid;
    const float4* wv4 = (const float4*)(Wm + (size_t)r * HID);
    float a[NPB];
    float bb = bias[r];
    #pragma unroll
    for (int j = 0; j < NPB; ++j) a[j] = bb;
    for (int k4 = 0; k4 < HID / 4; ++k4) {
        float4 w = wv4[k4];
        #pragma unroll
        for (int j = 0; j < NPB; ++j) {
            float4 e = rows4[j][k4];               // LDS broadcast b128
            a[j] += e.x * w.x + e.y * w.y + e.z * w.z + e.w * w.w;
        }
    }
    float* d0 = dst + (size_t)n0 * RED + r;
    #pragma unroll
    for (int j = 0; j < NPB; ++j)
        if (j < rowsN) d0[j * RED] = a[j];
}

// ---------- K2: stream + compact + gather + atomics + per-batch FC ticket ----------
__global__ __launch_bounds__(256) void k2_stream_gather_out(
        const float* __restrict__ nbr, const float* __restrict__ rel,
        const float* __restrict__ remb, const float* __restrict__ redge,
        const float* __restrict__ attn_ws, const float* __restrict__ fsum_ws,
        const float* __restrict__ diag, const float* __restrict__ b_l,
        const float* __restrict__ fcWT, const float* __restrict__ fc_b,
        float* __restrict__ h_g, float* __restrict__ h_p,
        int* __restrict__ done_b, float* __restrict__ out) {
    int bvm = blockIdx.x;                     // 0..2303
    int b   = bvm / (NV * MF);
    int tid = threadIdx.x;
    __shared__ int   nz_n[NZCAP];
    __shared__ float nz_v[NZCAP];
    __shared__ float rsum_s[NR];
    __shared__ int   cnt;
    __shared__ int   lastflag;
    __shared__ float z[2 * RED];
    __shared__ float part[2][OUTD];
    if (tid == 0) cnt = 0;

    // per-r constants (L2-resident, reused by all 2304 blocks)
    int r = tid;
    float dg = diag[r];
    float bl = b_l[r];
    float rg[NR];
    #pragma unroll
    for (int j = 0; j < NR; ++j) rg[j] = redge[j * RED + r];

    // ---- stream the 294 MB long pole: sum over t, nontemporal f4 loads ----
    const f4_t* base = (const f4_t*)(nbr + (size_t)bvm * MT * NF);  // row = 498 f4
    f4_t a0 = (f4_t)(0.f);
    f4_t a1 = (f4_t)(0.f);
    const bool has1 = (tid + 256) < (NF / 4);
    #pragma unroll 4
    for (int t = 0; t < MT; ++t) {
        const f4_t* r4 = base + t * (NF / 4);
        a0 += __builtin_nontemporal_load(r4 + tid);
        if (has1) a1 += __builtin_nontemporal_load(r4 + tid + 256);
    }
    float rs = 0.f;
    if (tid < NR) {
        const float* rb = rel + (size_t)bvm * MT * NR;
        #pragma unroll
        for (int t = 0; t < MT; ++t) rs += rb[t * NR + tid];
    }
    __syncthreads();                          // cnt=0 visible

    // ---- compact nonzeros into LDS ----
    int nb = tid * 4;
    #pragma unroll
    for (int c4 = 0; c4 < 4; ++c4)
        if (a0[c4] != 0.f) {
            int p = atomicAdd(&cnt, 1);
            if (p < NZCAP) { nz_n[p] = nb + c4; nz_v[p] = a0[c4]; }
        }
    if (has1) {
        nb = (tid + 256) * 4;
        #pragma unroll
        for (int c4 = 0; c4 < 4; ++c4)
            if (a1[c4] != 0.f) {
                int p = atomicAdd(&cnt, 1);
                if (p < NZCAP) { nz_n[p] = nb + c4; nz_v[p] = a1[c4]; }
            }
    }
    if (tid < NR) rsum_s[tid] = rs;
    __syncthreads();

    // ---- gather: 4-way MLP over L2 hits ----
    int c = min(cnt, NZCAP);
    float g0 = 0.f, g1 = 0.f, g2 = 0.f, g3 = 0.f;
    int i = 0;
    for (; i + 4 <= c; i += 4) {
        g0 += nz_v[i]     * remb[(size_t)nz_n[i]     * RED + r];
        g1 += nz_v[i + 1] * remb[(size_t)nz_n[i + 1] * RED + r];
        g2 += nz_v[i + 2] * remb[(size_t)nz_n[i + 2] * RED + r];
        g3 += nz_v[i + 3] * remb[(size_t)nz_n[i + 3] * RED + r];
    }
    for (; i < c; ++i)
        g0 += nz_v[i] * remb[(size_t)nz_n[i] * RED + r];
    float node = (g0 + g1) + (g2 + g3);
    float edge = 0.f;
    #pragma unroll
    for (int j = 0; j < NR; ++j) edge += rsum_s[j] * rg[j];

    float a  = attn_ws[bvm];                  // uniform broadcast loads
    float fs = fsum_ws[bvm];
    float agg = a * node + edge;
    float h = fmaxf(0.f, dg * agg + bl);
    atomicAdd(&h_g[b * RED + r], h);
    atomicAdd(&h_p[b * RED + r], fs * h);

    // ---- per-batch ticket: block drawing ticket NV*MF-1 does the FC for b ----
    __syncthreads();                          // all this block's atomics issued
    if (tid == 0) {
        __threadfence();                      // release our adds device-wide
        int old = __hip_atomic_fetch_add(&done_b[b], 1,
                                         __ATOMIC_ACQ_REL, __HIP_MEMORY_SCOPE_AGENT);
        lastflag = (old == NV * MF - 1);
    }
    __syncthreads();
    if (!lastflag) return;

    // last block of batch b: agent-scope coherent reads of the accumulators
    for (int j = tid; j < RED; j += 256) {
        z[j]       = __hip_atomic_load(&h_g[b * RED + j], __ATOMIC_RELAXED,
                                       __HIP_MEMORY_SCOPE_AGENT);
        z[RED + j] = __hip_atomic_load(&h_p[b * RED + j], __ATOMIC_RELAXED,
                                       __HIP_MEMORY_SCOPE_AGENT);
    }
    __syncthreads();
    int o = tid & 127, half = tid >> 7;
    if (o < OUTD) {
        float acc = 0.f;
        int j0 = half * RED;
        #pragma unroll 8
        for (int j = j0; j < j0 + RED; ++j)
            acc += z[j] * fcWT[j * OUTD + o];
        part[half][o] = acc;
    }
    __syncthreads();
    if (tid < OUTD) {
        float acc = part[0][tid] + part[1][tid] + fc_b[tid];
        out[b * OUTD + tid] = 1.f / (1.f + expf(-acc));
    }
}

extern "C" void kernel_launch(void* const* d_in, const int* in_sizes, int n_in,
                              void* d_out, int out_size, void* d_ws, size_t ws_size,
                              hipStream_t stream) {
    const float* feat    = (const float*)d_in[0];
    const float* nbr     = (const float*)d_in[1];
    const float* rel     = (const float*)d_in[2];
    const float* emb     = (const float*)d_in[3];
    const float* W_edge  = (const float*)d_in[4];
    const float* W_v     = (const float*)d_in[5];
    const float* W_r     = (const float*)d_in[6];
    const float* b_v     = (const float*)d_in[7];
    const float* b_r     = (const float*)d_in[8];
    const float* W_alpha = (const float*)d_in[9];
    const float* b_alpha = (const float*)d_in[10];
    const float* W_beta  = (const float*)d_in[11];
    const float* b_beta  = (const float*)d_in[12];
    const float* W_l     = (const float*)d_in[13];
    const float* b_l     = (const float*)d_in[14];
    const float* fc_W    = (const float*)d_in[15];
    const float* fc_b    = (const float*)d_in[16];

    float* ws    = (float*)d_ws;
    float* hg    = ws + WS_HG;
    float* hp    = ws + WS_HP;
    float* attn  = ws + WS_ATTN;
    float* fsum  = ws + WS_FSUM;
    float* remb  = ws + WS_REMB;
    float* redge = ws + WS_REDGE;
    float* fcWT  = ws + WS_FCWT;
    float* diag  = ws + WS_DIAG;
    int*   done  = (int*)(ws + WS_DONE);

    k1_prep_attn_reduce<<<K1_BLOCKS, 256, 0, stream>>>(
        feat, W_alpha, b_alpha, W_beta, b_beta,
        emb, W_edge, W_v, W_r, b_v, b_r, fc_W, W_l,
        ws, done, fcWT, diag, attn, fsum, remb, redge);
    k2_stream_gather_out<<<BS * NV * MF, 256, 0, stream>>>(
        nbr, rel, remb, redge, attn, fsum, diag, b_l, fcWT, fc_b,
        hg, hp, done, (float*)d_out);
}

// Round 3
// 440.333 us; speedup vs baseline: 1.3991x; 1.3991x over previous
//
#include <hip/hip_runtime.h>
#include <math.h>

#define BS   32
#define NV   6
#define MF   12
#define MT   16
#define NF   1992
#define NR   11
#define HID  128
#define RED  256
#define OUTD 90
#define GAMMA 0.1f
#define NZCAP 512   // E[nnz]=31.6, sigma=5.6 -> 512 is >80 sigma, bulletproof

typedef float f4_t __attribute__((ext_vector_type(4)));

// ---------------- workspace layout (float offsets) ----------------
#define WS_HG    0                        // 32*256
#define WS_HP    (WS_HG + BS*RED)         // 32*256  (hg+hp contiguous for zeroing)
#define WS_ATTN  (WS_HP + BS*RED)         // 2304
#define WS_FSUM  (WS_ATTN + BS*NV*MF)     // 2304
#define WS_REMB  (WS_FSUM + BS*NV*MF)     // 1992*256
#define WS_REDGE (WS_REMB + NF*RED)       // 11*256
#define WS_FCWT  (WS_REDGE + NR*RED)      // 512*90 (fc_W^T, j-major)
#define WS_DIAG  (WS_FCWT + 2*RED*OUTD)   // 256

#define N_ZERO (2*BS*RED)                 // 16384
#define N_FCWT (2*RED*OUTD)               // 46080
#define ZERO_BLOCKS (N_ZERO/256)          // 64
#define PREP2_BLOCKS ((N_FCWT + RED)/256) // 181 (fcWT then diag, exact)
#define ATTN_BLOCKS (BS*NV)               // 192
#define NPB 8
#define REMB_BLOCKS (NF/NPB)              // 249
#define REDGE_BLOCKS 2                    // 11 rows -> 8+3
#define K1_BLOCKS (ZERO_BLOCKS+PREP2_BLOCKS+ATTN_BLOCKS+REMB_BLOCKS+REDGE_BLOCKS)

// ---------- K1: zero | fcWT+diag | attention | remb+redge (no LDS transpose) ----------
// NOTE (round-2 lesson): no device-scope fences / acq-rel atomics anywhere —
// buffer_wbl2/buffer_inv from per-block release fences invalidated L2 and
// quadrupled the streaming kernel's time. Plain atomicAdd only.
__global__ __launch_bounds__(256) void k1_prep_attn_reduce(
        const float* __restrict__ feat, const float* __restrict__ W_alpha,
        const float* __restrict__ b_alpha, const float* __restrict__ W_beta,
        const float* __restrict__ b_beta,
        const float* __restrict__ emb, const float* __restrict__ W_edge,
        const float* __restrict__ W_v, const float* __restrict__ W_r,
        const float* __restrict__ b_v, const float* __restrict__ b_r,
        const float* __restrict__ fc_W, const float* __restrict__ W_l,
        float* __restrict__ ws_base,
        float* __restrict__ fcWT, float* __restrict__ diag,
        float* __restrict__ attn_ws, float* __restrict__ fsum_ws,
        float* __restrict__ remb, float* __restrict__ redge) {
    int blk = blockIdx.x;
    int tid = threadIdx.x;

    // union of per-role shared: ~4.2 KB -> 8 blocks/CU for every K1 role
    __shared__ float dot12[MF], fs12[MF];
    __shared__ float4 rows4[NPB][HID / 4];    // 4 KB: emb/W_edge rows, b128-broadcast

    if (blk < ZERO_BLOCKS) {                  // zero hg+hp (contiguous)
        ws_base[blk * 256 + tid] = 0.f;
        return;
    }
    blk -= ZERO_BLOCKS;

    if (blk < PREP2_BLOCKS) {                 // fcWT transpose + diag(W_l)
        int i = blk * 256 + tid;
        if (i < N_FCWT) {
            int jj = i / OUTD, o = i - jj * OUTD;
            fcWT[i] = fc_W[o * (2 * RED) + jj];
        } else {
            int j = i - N_FCWT;
            diag[j] = W_l[(size_t)j * RED + j];
        }
        return;
    }
    blk -= PREP2_BLOCKS;

    if (blk < ATTN_BLOCKS) {                  // one block per (b,v), wave per m
        int bv   = blk;
        int v    = bv % NV;
        int wave = tid >> 6;
        int lane = tid & 63;
        const float* base = feat + (size_t)bv * MF * NF;
        for (int m = wave; m < MF; m += 4) {
            const float4* rw = (const float4*)(base + (size_t)m * NF);
            const float4* wa = (const float4*)W_alpha;
            float da = 0.f, fs = 0.f;
            for (int i = lane; i < NF / 4; i += 64) {
                float4 x = rw[i];
                float4 w = wa[i];
                da += w.x * x.x + w.y * x.y + w.z * x.z + w.w * x.w;
                fs += x.x + x.y + x.z + x.w;
            }
            #pragma unroll
            for (int off = 32; off > 0; off >>= 1) {
                da += __shfl_xor(da, off);
                fs += __shfl_xor(fs, off);
            }
            if (lane == 0) { dot12[m] = da; fs12[m] = fs; }
        }
        __syncthreads();
        if (tid == 0) {
            float logits[MF];
            float mx = -1e30f;
            for (int m = 0; m < MF; ++m) { logits[m] = dot12[m] + b_alpha[m]; mx = fmaxf(mx, logits[m]); }
            float s = 0.f;
            for (int m = 0; m < MF; ++m) { logits[m] = expf(logits[m] - mx); s += logits[m]; }
            float inv = 1.f / s;
            float bdot = 0.f;
            for (int m = 0; m < MF; ++m) { logits[m] *= inv; bdot += W_beta[m] * logits[m]; }
            float lamb = expf(-GAMMA * (float)(NV - v));
            float beta = tanhf(bdot + b_beta[v]) * lamb;
            for (int m = 0; m < MF; ++m) {
                attn_ws[bv * MF + m] = logits[m] * beta;
                fsum_ws[bv * MF + m] = fs12[m];
            }
        }
        return;
    }
    blk -= ATTN_BLOCKS;

    // ---- remb (emb @ W_v^T + b_v) and redge (W_edge @ W_r^T + b_r) ----
    // thread r reads W row r directly (float4, 4x L1-line reuse);
    // emb rows staged once in LDS, read as broadcast ds_read_b128.
    bool isEdge = (blk >= REMB_BLOCKS);
    const float* src  = isEdge ? W_edge : emb;
    const float* Wm   = isEdge ? W_r : W_v;
    const float* bias = isEdge ? b_r : b_v;
    float* dst        = isEdge ? redge : remb;
    int n0    = (isEdge ? (blk - REMB_BLOCKS) : blk) * NPB;
    int rowsN = isEdge ? min(NPB, NR - n0) : NPB;

    const float4* src4 = (const float4*)(src + (size_t)n0 * HID);
    for (int idx = tid; idx < NPB * (HID / 4); idx += 256) {
        int j = idx >> 5, k4 = idx & 31;
        float4 z4 = {0.f, 0.f, 0.f, 0.f};
        rows4[j][k4] = (j < rowsN) ? src4[idx] : z4;
    }
    __syncthreads();

    int r = tid;
    const float4* wv4 = (const float4*)(Wm + (size_t)r * HID);
    float a[NPB];
    float bb = bias[r];
    #pragma unroll
    for (int j = 0; j < NPB; ++j) a[j] = bb;
    for (int k4 = 0; k4 < HID / 4; ++k4) {
        float4 w = wv4[k4];
        #pragma unroll
        for (int j = 0; j < NPB; ++j) {
            float4 e = rows4[j][k4];               // LDS broadcast b128
            a[j] += e.x * w.x + e.y * w.y + e.z * w.z + e.w * w.w;
        }
    }
    float* d0 = dst + (size_t)n0 * RED + r;
    #pragma unroll
    for (int j = 0; j < NPB; ++j)
        if (j < rowsN) d0[j * RED] = a[j];
}

// ---------- K2: fused nbr stream + compact (LDS) + gather + atomic accumulate ----------
__global__ __launch_bounds__(256) void k2_stream_gather(
        const float* __restrict__ nbr, const float* __restrict__ rel,
        const float* __restrict__ remb, const float* __restrict__ redge,
        const float* __restrict__ attn_ws, const float* __restrict__ fsum_ws,
        const float* __restrict__ diag, const float* __restrict__ b_l,
        float* __restrict__ h_g, float* __restrict__ h_p) {
    int bvm = blockIdx.x;                     // 0..2303
    int b   = bvm / (NV * MF);
    int tid = threadIdx.x;
    __shared__ int   nz_n[NZCAP];
    __shared__ float nz_v[NZCAP];
    __shared__ float rsum_s[NR];
    __shared__ int   cnt;
    if (tid == 0) cnt = 0;

    // per-r constants (L2-resident, reused by all 2304 blocks)
    int r = tid;
    float dg = diag[r];
    float bl = b_l[r];
    float rg[NR];
    #pragma unroll
    for (int j = 0; j < NR; ++j) rg[j] = redge[j * RED + r];

    // ---- stream the 294 MB long pole: sum over t, nontemporal f4 loads ----
    const f4_t* base = (const f4_t*)(nbr + (size_t)bvm * MT * NF);  // row = 498 f4
    f4_t a0 = (f4_t)(0.f);
    f4_t a1 = (f4_t)(0.f);
    const bool has1 = (tid + 256) < (NF / 4);
    #pragma unroll 4
    for (int t = 0; t < MT; ++t) {
        const f4_t* r4 = base + t * (NF / 4);
        a0 += __builtin_nontemporal_load(r4 + tid);
        if (has1) a1 += __builtin_nontemporal_load(r4 + tid + 256);
    }
    float rs = 0.f;
    if (tid < NR) {
        const float* rb = rel + (size_t)bvm * MT * NR;
        #pragma unroll
        for (int t = 0; t < MT; ++t) rs += rb[t * NR + tid];
    }
    __syncthreads();                          // cnt=0 visible

    // ---- compact nonzeros into LDS (never leaves the block) ----
    int nb = tid * 4;
    #pragma unroll
    for (int c4 = 0; c4 < 4; ++c4)
        if (a0[c4] != 0.f) {
            int p = atomicAdd(&cnt, 1);
            if (p < NZCAP) { nz_n[p] = nb + c4; nz_v[p] = a0[c4]; }
        }
    if (has1) {
        nb = (tid + 256) * 4;
        #pragma unroll
        for (int c4 = 0; c4 < 4; ++c4)
            if (a1[c4] != 0.f) {
                int p = atomicAdd(&cnt, 1);
                if (p < NZCAP) { nz_n[p] = nb + c4; nz_v[p] = a1[c4]; }
            }
    }
    if (tid < NR) rsum_s[tid] = rs;
    __syncthreads();

    // ---- gather: 4-way MLP over L2 hits ----
    int c = min(cnt, NZCAP);
    float g0 = 0.f, g1 = 0.f, g2 = 0.f, g3 = 0.f;
    int i = 0;
    for (; i + 4 <= c; i += 4) {
        g0 += nz_v[i]     * remb[(size_t)nz_n[i]     * RED + r];
        g1 += nz_v[i + 1] * remb[(size_t)nz_n[i + 1] * RED + r];
        g2 += nz_v[i + 2] * remb[(size_t)nz_n[i + 2] * RED + r];
        g3 += nz_v[i + 3] * remb[(size_t)nz_n[i + 3] * RED + r];
    }
    for (; i < c; ++i)
        g0 += nz_v[i] * remb[(size_t)nz_n[i] * RED + r];
    float node = (g0 + g1) + (g2 + g3);
    float edge = 0.f;
    #pragma unroll
    for (int j = 0; j < NR; ++j) edge += rsum_s[j] * rg[j];

    float a  = attn_ws[bvm];                  // uniform broadcast loads
    float fs = fsum_ws[bvm];
    float agg = a * node + edge;
    float h = fmaxf(0.f, dg * agg + bl);
    atomicAdd(&h_g[b * RED + r], h);          // plain device atomics: no fences
    atomicAdd(&h_p[b * RED + r], fs * h);
}

// ---------- K3: final FC + sigmoid ----------
__global__ __launch_bounds__(256) void k_out(
        const float* __restrict__ h_g, const float* __restrict__ h_p,
        const float* __restrict__ fcWT, const float* __restrict__ fc_b,
        float* __restrict__ out) {
    int b   = blockIdx.x;
    int tid = threadIdx.x;
    __shared__ float z[2 * RED];
    __shared__ float part[2][OUTD];
    for (int j = tid; j < RED; j += 256) {
        z[j]       = h_g[b * RED + j];
        z[RED + j] = h_p[b * RED + j];
    }
    __syncthreads();
    int o = tid & 127, half = tid >> 7;
    if (o < OUTD) {
        float acc = 0.f;
        int j0 = half * RED;
        #pragma unroll 8
        for (int j = j0; j < j0 + RED; ++j)
            acc += z[j] * fcWT[j * OUTD + o];
        part[half][o] = acc;
    }
    __syncthreads();
    if (tid < OUTD) {
        float acc = part[0][tid] + part[1][tid] + fc_b[tid];
        out[b * OUTD + tid] = 1.f / (1.f + expf(-acc));
    }
}

extern "C" void kernel_launch(void* const* d_in, const int* in_sizes, int n_in,
                              void* d_out, int out_size, void* d_ws, size_t ws_size,
                              hipStream_t stream) {
    const float* feat    = (const float*)d_in[0];
    const float* nbr     = (const float*)d_in[1];
    const float* rel     = (const float*)d_in[2];
    const float* emb     = (const float*)d_in[3];
    const float* W_edge  = (const float*)d_in[4];
    const float* W_v     = (const float*)d_in[5];
    const float* W_r     = (const float*)d_in[6];
    const float* b_v     = (const float*)d_in[7];
    const float* b_r     = (const float*)d_in[8];
    const float* W_alpha = (const float*)d_in[9];
    const float* b_alpha = (const float*)d_in[10];
    const float* W_beta  = (const float*)d_in[11];
    const float* b_beta  = (const float*)d_in[12];
    const float* W_l     = (const float*)d_in[13];
    const float* b_l     = (const float*)d_in[14];
    const float* fc_W    = (const float*)d_in[15];
    const float* fc_b    = (const float*)d_in[16];

    float* ws    = (float*)d_ws;
    float* hg    = ws + WS_HG;
    float* hp    = ws + WS_HP;
    float* attn  = ws + WS_ATTN;
    float* fsum  = ws + WS_FSUM;
    float* remb  = ws + WS_REMB;
    float* redge = ws + WS_REDGE;
    float* fcWT  = ws + WS_FCWT;
    float* diag  = ws + WS_DIAG;

    k1_prep_attn_reduce<<<K1_BLOCKS, 256, 0, stream>>>(
        feat, W_alpha, b_alpha, W_beta, b_beta,
        emb, W_edge, W_v, W_r, b_v, b_r, fc_W, W_l,
        ws, fcWT, diag, attn, fsum, remb, redge);
    k2_stream_gather<<<BS * NV * MF, 256, 0, stream>>>(
        nbr, rel, remb, redge, attn, fsum, diag, b_l, hg, hp);
    k_out<<<BS, 256, 0, stream>>>(hg, hp, fcWT, fc_b, (float*)d_out);
}